// Round 2
// baseline (673.774 us; speedup 1.0000x reference)
//
#include <hip/hip_runtime.h>
#include <hip/hip_bf16.h>
#include <math.h>

#define LLEN 30
#define DMOD 14
#define NH 8
#define NFF 50
#define LN_EPS 1e-5f
#define K1P 448           // padded inner dim for f (420 -> 448 = 14*32)
#define NREC_W1 14336     // 14 chunks * 4 slots * 256 rows
#define NREC_WR 3584      // 14 chunks * 4 slots * 64 rows
#define NREC_W2 2048      // 8 chunks * 4 slots * 64 rows

typedef unsigned short u16;
typedef unsigned int u32;
typedef __attribute__((ext_vector_type(8))) short s16x8;   // 8 bf16 = 4 VGPRs (MFMA A/B frag)
typedef __attribute__((ext_vector_type(4))) float f32x4;   // MFMA C/D frag

__device__ __forceinline__ float bflo(u32 v) {
  union { u32 u; float f; } w; w.u = v << 16; return w.f;
}
__device__ __forceinline__ u16 f2bf(float f) {
  union { float f; u32 u; } w; w.f = f;
  u32 x = w.u;
  x = (x + 0x7FFFu + ((x >> 16) & 1u)) >> 16;
  return (u16)x;
}
__device__ __forceinline__ u32 pk2(float lo, float hi) {
  return (u32)f2bf(lo) | ((u32)f2bf(hi) << 16);
}

// Branch-free exact-enough GELU: erf via Abramowitz-Stegun 7.1.26
// (max abs err 1.5e-7 on erf -> ~1e-7 on gelu; ocml erff is branchy and
// ~3-4x the instruction count under divergence).
__device__ __forceinline__ float gelu_fast(float a) {
  const float z  = fabsf(a) * 0.70710678118654752f;
  const float t  = __builtin_amdgcn_rcpf(1.f + 0.3275911f * z);
  const float p  = t * (0.254829592f + t * (-0.284496736f +
                   t * (1.421413741f + t * (-1.453152027f + t * 1.061405429f))));
  float e = 1.f - p * __expf(-z * z);
  e = copysignf(e, a);
  return 0.5f * a * (1.f + e);
}

// Exact replicate-pad 25-tap MA removal on one contiguous 30-float LDS row.
__device__ __forceinline__ void decomp_row_lds(float* row) {
  float xv[30];
  const float2* r2 = (const float2*)row;
  #pragma unroll
  for (int j = 0; j < 15; ++j) { float2 w = r2[j]; xv[2*j] = w.x; xv[2*j+1] = w.y; }
  float2* w2 = (float2*)row;
  float ws = 13.f * xv[0];
  #pragma unroll
  for (int j = 1; j <= 12; ++j) ws += xv[j];
  float rprev = xv[0] - ws * (1.f / 25.f);
  #pragma unroll
  for (int jj = 1; jj < 30; ++jj) {
    const int hi = (jj + 12 > 29) ? 29 : jj + 12;
    const int lo = (jj - 13 < 0) ? 0 : jj - 13;
    ws += xv[hi] - xv[lo];
    const float r = xv[jj] - ws * (1.f / 25.f);
    if (jj & 1) { w2[jj >> 1] = make_float2(rprev, r); } else { rprev = r; }
  }
}

// ============================ Front-end kernel ==============================
__global__ __launch_bounds__(64, 6) void fe_kernel(
    const float* __restrict__ x,
    const float* __restrict__ W_emb, const float* __restrict__ b_emb,
    const float* __restrict__ Wq, const float* __restrict__ bq,
    const float* __restrict__ Wk, const float* __restrict__ bk,
    const float* __restrict__ Wv, const float* __restrict__ bv,
    const float* __restrict__ Wo, const float* __restrict__ bo,
    const float* __restrict__ W_ff1, const float* __restrict__ W_ff2,
    const float* __restrict__ g_norm, const float* __restrict__ b_norm,
    const float* __restrict__ W_dy, const float* __restrict__ b_dy,
    const float* __restrict__ channels,
    u16* __restrict__ f_out, int Btot)
{
  const int t    = threadIdx.x;
  const int half = t >> 5;
  const int l    = t & 31;
  const int base = half << 5;
  const bool act = (l < LLEN);
  const int b    = blockIdx.x * 2 + half;
  const bool live = act && (b < Btot);

  __shared__ float pool[2][600];
  __shared__ float adjLDS[DMOD][16];
  __shared__ float MV[2][32];
  __shared__ float TW[2][4];
  __shared__ int   TD[2][4];

  // ---- P0: load x; lanes t<14 compute adj; zero-pad f row tail ----
  float xr[DMOD];
  if (live) {
    const float2* xp2 = (const float2*)(x + (size_t)b * 420 + l * DMOD);
    #pragma unroll
    for (int j = 0; j < 7; ++j) { float2 v = xp2[j]; xr[2*j] = v.x; xr[2*j+1] = v.y; }
  } else {
    #pragma unroll
    for (int d = 0; d < DMOD; ++d) xr[d] = 0.f;
  }
  if (l < 28 && b < Btot) f_out[(size_t)b * K1P + 420 + l] = (u16)0;
  if (t < DMOD) {
    float row[DMOD]; float m = -1e30f;
    #pragma unroll
    for (int j = 0; j < DMOD; ++j) { row[j] = channels[t * DMOD + j]; m = fmaxf(m, row[j]); }
    float s = 0.f;
    #pragma unroll
    for (int j = 0; j < DMOD; ++j) { row[j] = __expf(row[j] - m); s += row[j]; }
    const float inv = 1.f / s;
    #pragma unroll
    for (int j = 0; j < DMOD; ++j) adjLDS[t][j] = row[j] * inv;
  }

  // ---- P1: conv1d embed ----
  float xe[DMOD];
  #pragma unroll
  for (int o = 0; o < DMOD; ++o) xe[o] = b_emb[o];
  #pragma unroll
  for (int c = 0; c < DMOD; ++c) {
    float xm = __shfl(xr[c], t - 1);
    float xp = __shfl(xr[c], t + 1);
    xm = (l == 0) ? 0.f : xm;
    xp = (l >= LLEN - 1) ? 0.f : xp;
    const float xc = xr[c];
    #pragma unroll
    for (int o = 0; o < DMOD; ++o) {
      const float* wp = W_emb + o * (DMOD * 3) + c * 3;
      xe[o] += wp[0] * xm + wp[1] * xc + wp[2] * xp;
    }
  }

  // ---- P2: q,k,v ----
  float q[NH], k[NH], v[NH];
  #pragma unroll
  for (int h = 0; h < NH; ++h) { q[h] = bq[h]; k[h] = bk[h]; v[h] = bv[h]; }
  #pragma unroll
  for (int d = 0; d < DMOD; ++d) {
    const float e = xe[d];
    #pragma unroll
    for (int h = 0; h < NH; ++h) {
      q[h] += Wq[d * NH + h] * e;
      k[h] += Wk[d * NH + h] * e;
      v[h] += Wv[d * NH + h] * e;
    }
  }

  // ---- P3: autocorr ----
  if (act) {
    float2* qr = (float2*)&pool[half][l * 10];
    qr[0] = make_float2(q[0], q[1]); qr[1] = make_float2(q[2], q[3]);
    qr[2] = make_float2(q[4], q[5]); qr[3] = make_float2(q[6], q[7]);
    float2* kr = (float2*)&pool[half][300 + l * 10];
    kr[0] = make_float2(k[0], k[1]); kr[1] = make_float2(k[2], k[3]);
    kr[2] = make_float2(k[4], k[5]); kr[3] = make_float2(k[6], k[7]);
  }
  __syncthreads();
  if (act) {
    float acc = 0.f;
    #pragma unroll 5
    for (int s = 0; s < LLEN; ++s) {
      int rq = l + s; if (rq >= LLEN) rq -= LLEN;
      const float2* qa = (const float2*)&pool[half][rq * 10];
      const float2* ka = (const float2*)&pool[half][300 + s * 10];
      float2 a0 = qa[0], a1 = qa[1], a2 = qa[2], a3 = qa[3];
      float2 b0 = ka[0], b1 = ka[1], b2 = ka[2], b3 = ka[3];
      acc += a0.x * b0.x + a0.y * b0.y + a1.x * b1.x + a1.y * b1.y
           + a2.x * b2.x + a2.y * b2.y + a3.x * b3.x + a3.y * b3.y;
    }
    MV[half][l] = acc * (1.f / NH);
  }
  __syncthreads();

  // ---- P4: top-3 + softmax ----
  if (l == 0) {
    float v1 = -1e30f, v2 = -1e30f, v3 = -1e30f; int i1 = 0, i2 = 0, i3 = 0;
    for (int i = 0; i < LLEN; ++i) {
      const float vv = MV[half][i];
      if (vv > v1)      { v3 = v2; i3 = i2; v2 = v1; i2 = i1; v1 = vv; i1 = i; }
      else if (vv > v2) { v3 = v2; i3 = i2; v2 = vv; i2 = i; }
      else if (vv > v3) { v3 = vv; i3 = i; }
    }
    const float e2 = __expf(v2 - v1), e3 = __expf(v3 - v1);
    const float inv = 1.f / (1.f + e2 + e3);
    TW[half][0] = inv; TW[half][1] = e2 * inv; TW[half][2] = e3 * inv;
    TD[half][0] = i1; TD[half][1] = i2; TD[half][2] = i3;
  }
  __syncthreads();

  // ---- P5: weighted circular gather ----
  float agg[NH];
  #pragma unroll
  for (int h = 0; h < NH; ++h) agg[h] = 0.f;
  #pragma unroll
  for (int kk = 0; kk < 3; ++kk) {
    const float w = TW[half][kk];
    const int dd = TD[half][kk];
    int sidx = l + dd; if (sidx >= LLEN) sidx -= LLEN;
    const int src = base + sidx;
    #pragma unroll
    for (int h = 0; h < NH; ++h) agg[h] += w * __shfl(v[h], src);
  }

  // ---- P6: out-proj + residual ----
  #pragma unroll
  for (int d = 0; d < DMOD; ++d) {
    float a = bo[d];
    #pragma unroll
    for (int h = 0; h < NH; ++h) a += agg[h] * Wo[h * DMOD + d];
    xe[d] += a;
  }
  __syncthreads();

  // ---- P7: decomp #1 ----
  if (act) {
    #pragma unroll
    for (int d = 0; d < DMOD; ++d) pool[half][d * LLEN + l] = xe[d];
  }
  __syncthreads();
  if (l < DMOD) decomp_row_lds(&pool[half][l * LLEN]);
  __syncthreads();
  float s1[DMOD];
  if (act) {
    #pragma unroll
    for (int d = 0; d < DMOD; ++d) s1[d] = pool[half][d * LLEN + l];
  } else {
    #pragma unroll
    for (int d = 0; d < DMOD; ++d) s1[d] = 0.f;
  }
  __syncthreads();

  // ---- P8: FFN (fast-erf GELU) ----
  float y[DMOD];
  #pragma unroll
  for (int d = 0; d < DMOD; ++d) y[d] = 0.f;
  #pragma unroll 5
  for (int f = 0; f < NFF; ++f) {
    float a = 0.f;
    #pragma unroll
    for (int d = 0; d < DMOD; ++d) a += s1[d] * W_ff1[d * NFF + f];
    const float g = gelu_fast(a);
    #pragma unroll
    for (int d = 0; d < DMOD; ++d) y[d] += g * W_ff2[f * DMOD + d];
  }

  // ---- P9: decomp #2 ----
  if (act) {
    #pragma unroll
    for (int d = 0; d < DMOD; ++d) pool[half][d * LLEN + l] = s1[d] + y[d];
  }
  __syncthreads();
  if (l < DMOD) decomp_row_lds(&pool[half][l * LLEN]);
  __syncthreads();

  // ---- P10: LayerNorm over D ----
  float ln[DMOD];
  if (act) {
    float s2v[DMOD];
    #pragma unroll
    for (int d = 0; d < DMOD; ++d) s2v[d] = pool[half][d * LLEN + l];
    float m = 0.f;
    #pragma unroll
    for (int d = 0; d < DMOD; ++d) m += s2v[d];
    m *= (1.f / DMOD);
    float va = 0.f;
    #pragma unroll
    for (int d = 0; d < DMOD; ++d) { const float z = s2v[d] - m; va += z * z; }
    va *= (1.f / DMOD);
    const float inv = rsqrtf(va + LN_EPS);
    #pragma unroll
    for (int d = 0; d < DMOD; ++d) ln[d] = (s2v[d] - m) * inv * g_norm[d] + b_norm[d];
  } else {
    #pragma unroll
    for (int d = 0; d < DMOD; ++d) ln[d] = 0.f;
  }
  __syncthreads();

  // ---- P11: u = adj @ ln ----
  float u[DMOD];
  #pragma unroll
  for (int i = 0; i < DMOD; ++i) {
    const float4* ar = (const float4*)&adjLDS[i][0];
    const float4 c0 = ar[0], c1 = ar[1], c2 = ar[2];
    const float2 c3 = ((const float2*)ar)[6];
    u[i] = c0.x * ln[0] + c0.y * ln[1] + c0.z * ln[2] + c0.w * ln[3]
         + c1.x * ln[4] + c1.y * ln[5] + c1.z * ln[6] + c1.w * ln[7]
         + c2.x * ln[8] + c2.y * ln[9] + c2.z * ln[10] + c2.w * ln[11]
         + c3.x * ln[12] + c3.y * ln[13];
  }
  if (act) {
    float4* ur = (float4*)&pool[half][l * 16];
    ur[0] = make_float4(u[0], u[1], u[2], u[3]);
    ur[1] = make_float4(u[4], u[5], u[6], u[7]);
    ur[2] = make_float4(u[8], u[9], u[10], u[11]);
    ((float2*)ur)[6] = make_float2(u[12], u[13]);
  }
  __syncthreads();

  // ---- P12: dy + write f (stride 448, bf16) ----
  if (live) {
    float acc[DMOD];
    #pragma unroll
    for (int i = 0; i < DMOD; ++i) acc[i] = 0.f;
    #pragma unroll 5
    for (int lp = 0; lp < LLEN; ++lp) {
      const float wd = W_dy[lp * LLEN + l];
      const float4* ur = (const float4*)&pool[half][lp * 16];
      const float4 a0 = ur[0], a1 = ur[1], a2 = ur[2];
      const float2 a3 = ((const float2*)ur)[6];
      acc[0] += a0.x * wd;  acc[1] += a0.y * wd;  acc[2]  += a0.z * wd;  acc[3]  += a0.w * wd;
      acc[4] += a1.x * wd;  acc[5] += a1.y * wd;  acc[6]  += a1.z * wd;  acc[7]  += a1.w * wd;
      acc[8] += a2.x * wd;  acc[9] += a2.y * wd;  acc[10] += a2.z * wd;  acc[11] += a2.w * wd;
      acc[12] += a3.x * wd; acc[13] += a3.y * wd;
    }
    const float bd = b_dy[l];
    u16* fo = f_out + (size_t)b * K1P + l;
    #pragma unroll
    for (int i = 0; i < DMOD; ++i)
      fo[i * LLEN] = f2bf(fmaxf(acc[i] + bd, 0.f));
  }
}

// ========================= Weight prep (one-time-ish) =======================
__global__ void prep_kernel(const float* __restrict__ W1,
                            const float* __restrict__ Wres,
                            const float* __restrict__ W2,
                            u16* __restrict__ w1s,
                            u16* __restrict__ wrh, u16* __restrict__ wrl,
                            u16* __restrict__ w2h, u16* __restrict__ w2l)
{
  const int idx = blockIdx.x * 256 + threadIdx.x;
  if (idx < NREC_W1) {
    const int n1 = idx & 255;
    const int cs = idx >> 8;
    const int k0 = cs * 8;
    union { u16 h[8]; uint4 q; } R;
    #pragma unroll
    for (int i = 0; i < 8; ++i) {
      const int k = k0 + i;
      const float w = (k < 420) ? W1[k * 256 + n1] : 0.f;
      R.h[i] = f2bf(w);
    }
    *((uint4*)(w1s + (size_t)idx * 8)) = R.q;
  } else if (idx < NREC_W1 + NREC_WR) {
    const int id = idx - NREC_W1;
    const int row = id & 63;
    const int cs = id >> 6;
    const int k0 = cs * 8;
    union { u16 h[8]; uint4 q; } Rh, Rl;
    #pragma unroll
    for (int i = 0; i < 8; ++i) {
      const int k = k0 + i;
      const float w = (k < 420) ? Wres[k * 64 + row] : 0.f;
      const u16 hh = f2bf(w);
      Rh.h[i] = hh;
      Rl.h[i] = f2bf(w - bflo((u32)hh));
    }
    *((uint4*)(wrh + (size_t)id * 8)) = Rh.q;
    *((uint4*)(wrl + (size_t)id * 8)) = Rl.q;
  } else if (idx < NREC_W1 + NREC_WR + NREC_W2) {
    const int id = idx - NREC_W1 - NREC_WR;
    const int row = id & 63;
    const int cs = id >> 6;
    const int k0 = cs * 8;
    union { u16 h[8]; uint4 q; } Rh, Rl;
    #pragma unroll
    for (int i = 0; i < 8; ++i) {
      const float w = W2[(k0 + i) * 64 + row];
      const u16 hh = f2bf(w);
      Rh.h[i] = hh;
      Rl.h[i] = f2bf(w - bflo((u32)hh));
    }
    *((uint4*)(w2h + (size_t)id * 8)) = Rh.q;
    *((uint4*)(w2l + (size_t)id * 8)) = Rl.q;
  }
}

// ============================ MFMA MLP head =================================
__global__ __launch_bounds__(256, 3) void head_mfma(
    const u16* __restrict__ f, const u16* __restrict__ w1s,
    const u16* __restrict__ wrh, const u16* __restrict__ wrl,
    const u16* __restrict__ w2h, const u16* __restrict__ w2l,
    const float* __restrict__ b1, const float* __restrict__ b2,
    const float* __restrict__ bres, const float* __restrict__ g_ln,
    const float* __restrict__ b_ln, const float* __restrict__ W3,
    const float* __restrict__ b3, float* __restrict__ out, int Btot)
{
  const int lane = threadIdx.x & 63;
  const int wv   = threadIdx.x >> 6;
  const int g    = lane >> 4;       // k-slot / row-quadrant
  const int m    = lane & 15;       // sample within wave
  const int samp = blockIdx.x * 64 + wv * 16 + m;
  const int srow = (samp < Btot) ? samp : (Btot - 1);

  // f fragments: fr[c] = f[samp][32c + 8g .. +7]
  s16x8 fr[14];
  const u16* fp = f + (size_t)srow * K1P + g * 8;
  #pragma unroll
  for (int c = 0; c < 14; ++c)
    fr[c] = *((const s16x8*)(fp + 32 * c));

  const f32x4 zero4 = {0.f, 0.f, 0.f, 0.f};

  // ---- residual: r = f @ Wres (hi + lo); 4 independent nt chains ----
  f32x4 ac3[4] = {zero4, zero4, zero4, zero4};
  #pragma unroll
  for (int c = 0; c < 14; ++c) {
    const int bo = (c * 4 + g) * 512 + m * 8;
    #pragma unroll
    for (int nt = 0; nt < 4; ++nt) {
      const s16x8 ah = *((const s16x8*)(wrh + bo + nt * 128));
      ac3[nt] = __builtin_amdgcn_mfma_f32_16x16x32_bf16(ah, fr[c], ac3[nt], 0, 0, 0);
    }
    #pragma unroll
    for (int nt = 0; nt < 4; ++nt) {
      const s16x8 al = *((const s16x8*)(wrl + bo + nt * 128));
      ac3[nt] = __builtin_amdgcn_mfma_f32_16x16x32_bf16(al, fr[c], ac3[nt], 0, 0, 0);
    }
  }

  // ---- h = relu(f@W1 + b1) ; out2 = h @ W2 (hi + lo) ----
  f32x4 ac2[4] = {zero4, zero4, zero4, zero4};
  const int ap0 = ((g & 1) << 7) + (m << 2);
  const int ap1 = ap0 + 64;
  #pragma unroll 2
  for (int j = 0; j < 8; ++j) {
    // split accumulate chains (2 partials each) to halve MFMA dep latency
    f32x4 ha0 = zero4, ha1 = zero4, hb0 = zero4, hb1 = zero4;
    #pragma unroll
    for (int c = 0; c < 14; c += 2) {
      const int boA = (c * 4 + g) * 2048 + m * 8;
      const int boB = ((c + 1) * 4 + g) * 2048 + m * 8;
      const s16x8 wa0 = *((const s16x8*)(w1s + boA + (2 * j) * 128));
      const s16x8 wb0 = *((const s16x8*)(w1s + boA + (2 * j + 1) * 128));
      const s16x8 wa1 = *((const s16x8*)(w1s + boB + (2 * j) * 128));
      const s16x8 wb1 = *((const s16x8*)(w1s + boB + (2 * j + 1) * 128));
      ha0 = __builtin_amdgcn_mfma_f32_16x16x32_bf16(wa0, fr[c], ha0, 0, 0, 0);
      hb0 = __builtin_amdgcn_mfma_f32_16x16x32_bf16(wb0, fr[c], hb0, 0, 0, 0);
      ha1 = __builtin_amdgcn_mfma_f32_16x16x32_bf16(wa1, fr[c + 1], ha1, 0, 0, 0);
      hb1 = __builtin_amdgcn_mfma_f32_16x16x32_bf16(wb1, fr[c + 1], hb1, 0, 0, 0);
    }
    const f32x4 ha = ha0 + ha1;
    const f32x4 hb = hb0 + hb1;
    const int f0 = 32 * j + 4 * g;
    const float H00 = fmaxf(ha[0] + b1[f0 + 0], 0.f);
    const float H01 = fmaxf(ha[1] + b1[f0 + 1], 0.f);
    const float H02 = fmaxf(ha[2] + b1[f0 + 2], 0.f);
    const float H03 = fmaxf(ha[3] + b1[f0 + 3], 0.f);
    const float H10 = fmaxf(hb[0] + b1[f0 + 16], 0.f);
    const float H11 = fmaxf(hb[1] + b1[f0 + 17], 0.f);
    const float H12 = fmaxf(hb[2] + b1[f0 + 18], 0.f);
    const float H13 = fmaxf(hb[3] + b1[f0 + 19], 0.f);
    const u32 PK00 = pk2(H00, H01), PK01 = pk2(H10, H11);
    const u32 PK10 = pk2(H02, H03), PK11 = pk2(H12, H13);
    union { u32 u[4]; s16x8 v; } bb;
    {
      const u32 r0 = (u32)__builtin_amdgcn_ds_bpermute(ap0, (int)PK00);
      const u32 r1 = (u32)__builtin_amdgcn_ds_bpermute(ap0, (int)PK01);
      bb.u[0] = (g & 2) ? r1 : r0;
    }
    {
      const u32 r0 = (u32)__builtin_amdgcn_ds_bpermute(ap0, (int)PK10);
      const u32 r1 = (u32)__builtin_amdgcn_ds_bpermute(ap0, (int)PK11);
      bb.u[1] = (g & 2) ? r1 : r0;
    }
    {
      const u32 r0 = (u32)__builtin_amdgcn_ds_bpermute(ap1, (int)PK00);
      const u32 r1 = (u32)__builtin_amdgcn_ds_bpermute(ap1, (int)PK01);
      bb.u[2] = (g & 2) ? r1 : r0;
    }
    {
      const u32 r0 = (u32)__builtin_amdgcn_ds_bpermute(ap1, (int)PK10);
      const u32 r1 = (u32)__builtin_amdgcn_ds_bpermute(ap1, (int)PK11);
      bb.u[3] = (g & 2) ? r1 : r0;
    }
    const int bo2 = (j * 4 + g) * 512 + m * 8;
    #pragma unroll
    for (int nt = 0; nt < 4; ++nt) {
      const s16x8 a2h = *((const s16x8*)(w2h + bo2 + nt * 128));
      ac2[nt] = __builtin_amdgcn_mfma_f32_16x16x32_bf16(a2h, bb.v, ac2[nt], 0, 0, 0);
    }
    #pragma unroll
    for (int nt = 0; nt < 4; ++nt) {
      const s16x8 a2l = *((const s16x8*)(w2l + bo2 + nt * 128));
      ac2[nt] = __builtin_amdgcn_mfma_f32_16x16x32_bf16(a2l, bb.v, ac2[nt], 0, 0, 0);
    }
  }

  // ---- LayerNorm over 64 features + dot W3 ----
  float vals[4][4];
  float s1 = 0.f, sq = 0.f;
  #pragma unroll
  for (int nt = 0; nt < 4; ++nt) {
    #pragma unroll
    for (int r = 0; r < 4; ++r) {
      const int fe = 16 * nt + 4 * g + r;
      const float val = ac2[nt][r] + ac3[nt][r] + b2[fe] + bres[fe];
      vals[nt][r] = val; s1 += val; sq += val * val;
    }
  }
  s1 += __shfl_xor(s1, 16); s1 += __shfl_xor(s1, 32);
  sq += __shfl_xor(sq, 16); sq += __shfl_xor(sq, 32);
  const float mean = s1 * (1.f / 64.f);
  const float var  = sq * (1.f / 64.f) - mean * mean;
  const float inv  = rsqrtf(var + LN_EPS);
  float pr = 0.f;
  #pragma unroll
  for (int nt = 0; nt < 4; ++nt) {
    #pragma unroll
    for (int r = 0; r < 4; ++r) {
      const int fe = 16 * nt + 4 * g + r;
      const float n = (vals[nt][r] - mean) * inv * g_ln[fe] + b_ln[fe];
      pr += n * W3[fe];
    }
  }
  pr += __shfl_xor(pr, 16); pr += __shfl_xor(pr, 32);
  if (g == 0 && samp < Btot) out[samp] = pr + b3[0];
}

extern "C" void kernel_launch(void* const* d_in, const int* in_sizes, int n_in,
                              void* d_out, int out_size, void* d_ws, size_t ws_size,
                              hipStream_t stream) {
  const float* x        = (const float*)d_in[0];
  const float* W_emb    = (const float*)d_in[1];
  const float* b_emb    = (const float*)d_in[2];
  const float* Wq       = (const float*)d_in[3];
  const float* bq       = (const float*)d_in[4];
  const float* Wk       = (const float*)d_in[5];
  const float* bk       = (const float*)d_in[6];
  const float* Wv       = (const float*)d_in[7];
  const float* bv       = (const float*)d_in[8];
  const float* Wo       = (const float*)d_in[9];
  const float* bo       = (const float*)d_in[10];
  const float* W_ff1    = (const float*)d_in[11];
  const float* W_ff2    = (const float*)d_in[12];
  const float* g_norm   = (const float*)d_in[13];
  const float* b_norm   = (const float*)d_in[14];
  const float* W_dy     = (const float*)d_in[15];
  const float* b_dy     = (const float*)d_in[16];
  const float* channels = (const float*)d_in[17];
  const float* W1       = (const float*)d_in[18];
  const float* b1       = (const float*)d_in[19];
  const float* W2       = (const float*)d_in[20];
  const float* b2       = (const float*)d_in[21];
  const float* Wres     = (const float*)d_in[22];
  const float* bres     = (const float*)d_in[23];
  const float* g_ln     = (const float*)d_in[24];
  const float* b_ln     = (const float*)d_in[25];
  const float* W3       = (const float*)d_in[26];
  const float* b3       = (const float*)d_in[27];

  const int B = in_sizes[0] / (LLEN * DMOD);

  u16* fbuf = (u16*)d_ws;
  u16* w1s  = fbuf + (size_t)B * K1P;
  u16* wrh  = w1s + (size_t)NREC_W1 * 8;
  u16* wrl  = wrh + (size_t)NREC_WR * 8;
  u16* w2h  = wrl + (size_t)NREC_WR * 8;
  u16* w2l  = w2h + (size_t)NREC_W2 * 8;

  prep_kernel<<<78, 256, 0, stream>>>(W1, Wres, W2, w1s, wrh, wrl, w2h, w2l);

  const int nb_fe = (B + 1) / 2;
  fe_kernel<<<nb_fe, 64, 0, stream>>>(x, W_emb, b_emb, Wq, bq, Wk, bk, Wv, bv, Wo, bo,
                                      W_ff1, W_ff2, g_norm, b_norm, W_dy, b_dy, channels,
                                      fbuf, B);

  const int nb_h = (B + 63) / 64;
  head_mfma<<<nb_h, 256, 0, stream>>>(fbuf, w1s, wrh, wrl, w2h, w2l,
                                      b1, b2, bres, g_ln, b_ln, W3, b3,
                                      (float*)d_out, B);
}

// Round 3
// 671.684 us; speedup vs baseline: 1.0031x; 1.0031x over previous
//
#include <hip/hip_runtime.h>
#include <hip/hip_bf16.h>
#include <math.h>

#define LLEN 30
#define DMOD 14
#define NH 8
#define NFF 50
#define LN_EPS 1e-5f
#define K1P 448           // padded inner dim for f (420 -> 448 = 14*32)
#define NREC_W1 14336     // 14 chunks * 4 slots * 256 rows
#define NREC_WR 3584      // 14 chunks * 4 slots * 64 rows
#define NREC_W2 2048      // 8 chunks * 4 slots * 64 rows

typedef unsigned short u16;
typedef unsigned int u32;
typedef __attribute__((ext_vector_type(8))) short s16x8;   // 8 bf16 = 4 VGPRs (MFMA A/B frag)
typedef __attribute__((ext_vector_type(4))) float f32x4;   // MFMA C/D frag

__device__ __forceinline__ float bflo(u32 v) {
  union { u32 u; float f; } w; w.u = v << 16; return w.f;
}
__device__ __forceinline__ u16 f2bf(float f) {
  union { float f; u32 u; } w; w.f = f;
  u32 x = w.u;
  x = (x + 0x7FFFu + ((x >> 16) & 1u)) >> 16;
  return (u16)x;
}
__device__ __forceinline__ u32 pk2(float lo, float hi) {
  return (u32)f2bf(lo) | ((u32)f2bf(hi) << 16);
}

// Branch-free GELU: erf via Abramowitz-Stegun 7.1.26 (max abs err ~1.5e-7).
__device__ __forceinline__ float gelu_fast(float a) {
  const float z  = fabsf(a) * 0.70710678118654752f;
  const float t  = __builtin_amdgcn_rcpf(1.f + 0.3275911f * z);
  const float p  = t * (0.254829592f + t * (-0.284496736f +
                   t * (1.421413741f + t * (-1.453152027f + t * 1.061405429f))));
  float e = 1.f - p * __expf(-z * z);
  e = copysignf(e, a);
  return 0.5f * a * (1.f + e);
}

// Exact replicate-pad 25-tap MA removal on one contiguous 30-float LDS row.
__device__ __forceinline__ void decomp_row_lds(float* row) {
  float xv[30];
  const float2* r2 = (const float2*)row;
  #pragma unroll
  for (int j = 0; j < 15; ++j) { float2 w = r2[j]; xv[2*j] = w.x; xv[2*j+1] = w.y; }
  float2* w2 = (float2*)row;
  float ws = 13.f * xv[0];
  #pragma unroll
  for (int j = 1; j <= 12; ++j) ws += xv[j];
  float rprev = xv[0] - ws * (1.f / 25.f);
  #pragma unroll
  for (int jj = 1; jj < 30; ++jj) {
    const int hi = (jj + 12 > 29) ? 29 : jj + 12;
    const int lo = (jj - 13 < 0) ? 0 : jj - 13;
    ws += xv[hi] - xv[lo];
    const float r = xv[jj] - ws * (1.f / 25.f);
    if (jj & 1) { w2[jj >> 1] = make_float2(rprev, r); } else { rprev = r; }
  }
}

// ============================ Front-end kernel ==============================
// launch_bounds (64,3): VGPR cap ~170 so the whole working set stays in
// registers. (64,6) forced a 40-VGPR allocation -> scratch spills (~50 MB of
// extra write traffic, reload stalls).
__global__ __launch_bounds__(64, 3) void fe_kernel(
    const float* __restrict__ x,
    const float* __restrict__ W_emb, const float* __restrict__ b_emb,
    const float* __restrict__ Wq, const float* __restrict__ bq,
    const float* __restrict__ Wk, const float* __restrict__ bk,
    const float* __restrict__ Wv, const float* __restrict__ bv,
    const float* __restrict__ Wo, const float* __restrict__ bo,
    const float* __restrict__ W_ff1, const float* __restrict__ W_ff2,
    const float* __restrict__ g_norm, const float* __restrict__ b_norm,
    const float* __restrict__ W_dy, const float* __restrict__ b_dy,
    const float* __restrict__ channels,
    u16* __restrict__ f_out, int Btot)
{
  const int t    = threadIdx.x;
  const int half = t >> 5;
  const int l    = t & 31;
  const int base = half << 5;
  const bool act = (l < LLEN);
  const int b    = blockIdx.x * 2 + half;
  const bool live = act && (b < Btot);

  __shared__ float pool[2][600];
  __shared__ float adjLDS[DMOD][16];
  __shared__ float MV[2][32];
  __shared__ float TW[2][4];
  __shared__ int   TD[2][4];

  // ---- P0: load x; lanes t<14 compute adj ----
  float xr[DMOD];
  if (live) {
    const float2* xp2 = (const float2*)(x + (size_t)b * 420 + l * DMOD);
    #pragma unroll
    for (int j = 0; j < 7; ++j) { float2 v = xp2[j]; xr[2*j] = v.x; xr[2*j+1] = v.y; }
  } else {
    #pragma unroll
    for (int d = 0; d < DMOD; ++d) xr[d] = 0.f;
  }
  if (t < DMOD) {
    float row[DMOD]; float m = -1e30f;
    #pragma unroll
    for (int j = 0; j < DMOD; ++j) { row[j] = channels[t * DMOD + j]; m = fmaxf(m, row[j]); }
    float s = 0.f;
    #pragma unroll
    for (int j = 0; j < DMOD; ++j) { row[j] = __expf(row[j] - m); s += row[j]; }
    const float inv = 1.f / s;
    #pragma unroll
    for (int j = 0; j < DMOD; ++j) adjLDS[t][j] = row[j] * inv;
  }

  // ---- P1: conv1d embed ----
  float xe[DMOD];
  #pragma unroll
  for (int o = 0; o < DMOD; ++o) xe[o] = b_emb[o];
  #pragma unroll
  for (int c = 0; c < DMOD; ++c) {
    float xm = __shfl(xr[c], t - 1);
    float xp = __shfl(xr[c], t + 1);
    xm = (l == 0) ? 0.f : xm;
    xp = (l >= LLEN - 1) ? 0.f : xp;
    const float xc = xr[c];
    #pragma unroll
    for (int o = 0; o < DMOD; ++o) {
      const float* wp = W_emb + o * (DMOD * 3) + c * 3;
      xe[o] += wp[0] * xm + wp[1] * xc + wp[2] * xp;
    }
  }

  // ---- P2: q,k,v ----
  float q[NH], k[NH], v[NH];
  #pragma unroll
  for (int h = 0; h < NH; ++h) { q[h] = bq[h]; k[h] = bk[h]; v[h] = bv[h]; }
  #pragma unroll
  for (int d = 0; d < DMOD; ++d) {
    const float e = xe[d];
    #pragma unroll
    for (int h = 0; h < NH; ++h) {
      q[h] += Wq[d * NH + h] * e;
      k[h] += Wk[d * NH + h] * e;
      v[h] += Wv[d * NH + h] * e;
    }
  }

  // ---- P3: autocorr ----
  if (act) {
    float2* qr = (float2*)&pool[half][l * 10];
    qr[0] = make_float2(q[0], q[1]); qr[1] = make_float2(q[2], q[3]);
    qr[2] = make_float2(q[4], q[5]); qr[3] = make_float2(q[6], q[7]);
    float2* kr = (float2*)&pool[half][300 + l * 10];
    kr[0] = make_float2(k[0], k[1]); kr[1] = make_float2(k[2], k[3]);
    kr[2] = make_float2(k[4], k[5]); kr[3] = make_float2(k[6], k[7]);
  }
  __syncthreads();
  if (act) {
    float acc = 0.f;
    #pragma unroll 5
    for (int s = 0; s < LLEN; ++s) {
      int rq = l + s; if (rq >= LLEN) rq -= LLEN;
      const float2* qa = (const float2*)&pool[half][rq * 10];
      const float2* ka = (const float2*)&pool[half][300 + s * 10];
      float2 a0 = qa[0], a1 = qa[1], a2 = qa[2], a3 = qa[3];
      float2 b0 = ka[0], b1 = ka[1], b2 = ka[2], b3 = ka[3];
      acc += a0.x * b0.x + a0.y * b0.y + a1.x * b1.x + a1.y * b1.y
           + a2.x * b2.x + a2.y * b2.y + a3.x * b3.x + a3.y * b3.y;
    }
    MV[half][l] = acc * (1.f / NH);
  }
  __syncthreads();

  // ---- P4: top-3 + softmax ----
  if (l == 0) {
    float v1 = -1e30f, v2 = -1e30f, v3 = -1e30f; int i1 = 0, i2 = 0, i3 = 0;
    for (int i = 0; i < LLEN; ++i) {
      const float vv = MV[half][i];
      if (vv > v1)      { v3 = v2; i3 = i2; v2 = v1; i2 = i1; v1 = vv; i1 = i; }
      else if (vv > v2) { v3 = v2; i3 = i2; v2 = vv; i2 = i; }
      else if (vv > v3) { v3 = vv; i3 = i; }
    }
    const float e2 = __expf(v2 - v1), e3 = __expf(v3 - v1);
    const float inv = 1.f / (1.f + e2 + e3);
    TW[half][0] = inv; TW[half][1] = e2 * inv; TW[half][2] = e3 * inv;
    TD[half][0] = i1; TD[half][1] = i2; TD[half][2] = i3;
  }
  __syncthreads();

  // ---- P5: weighted circular gather ----
  float agg[NH];
  #pragma unroll
  for (int h = 0; h < NH; ++h) agg[h] = 0.f;
  #pragma unroll
  for (int kk = 0; kk < 3; ++kk) {
    const float w = TW[half][kk];
    const int dd = TD[half][kk];
    int sidx = l + dd; if (sidx >= LLEN) sidx -= LLEN;
    const int src = base + sidx;
    #pragma unroll
    for (int h = 0; h < NH; ++h) agg[h] += w * __shfl(v[h], src);
  }

  // ---- P6: out-proj + residual ----
  #pragma unroll
  for (int d = 0; d < DMOD; ++d) {
    float a = bo[d];
    #pragma unroll
    for (int h = 0; h < NH; ++h) a += agg[h] * Wo[h * DMOD + d];
    xe[d] += a;
  }
  __syncthreads();

  // ---- P7: decomp #1 ----
  if (act) {
    #pragma unroll
    for (int d = 0; d < DMOD; ++d) pool[half][d * LLEN + l] = xe[d];
  }
  __syncthreads();
  if (l < DMOD) decomp_row_lds(&pool[half][l * LLEN]);
  __syncthreads();
  float s1[DMOD];
  if (act) {
    #pragma unroll
    for (int d = 0; d < DMOD; ++d) s1[d] = pool[half][d * LLEN + l];
  } else {
    #pragma unroll
    for (int d = 0; d < DMOD; ++d) s1[d] = 0.f;
  }
  __syncthreads();

  // ---- P8: FFN (fast-erf GELU) ----
  float y[DMOD];
  #pragma unroll
  for (int d = 0; d < DMOD; ++d) y[d] = 0.f;
  #pragma unroll 5
  for (int f = 0; f < NFF; ++f) {
    float a = 0.f;
    #pragma unroll
    for (int d = 0; d < DMOD; ++d) a += s1[d] * W_ff1[d * NFF + f];
    const float g = gelu_fast(a);
    #pragma unroll
    for (int d = 0; d < DMOD; ++d) y[d] += g * W_ff2[f * DMOD + d];
  }

  // ---- P9: decomp #2 ----
  if (act) {
    #pragma unroll
    for (int d = 0; d < DMOD; ++d) pool[half][d * LLEN + l] = s1[d] + y[d];
  }
  __syncthreads();
  if (l < DMOD) decomp_row_lds(&pool[half][l * LLEN]);
  __syncthreads();

  // ---- P10: LayerNorm over D ----
  float ln[DMOD];
  if (act) {
    float s2v[DMOD];
    #pragma unroll
    for (int d = 0; d < DMOD; ++d) s2v[d] = pool[half][d * LLEN + l];
    float m = 0.f;
    #pragma unroll
    for (int d = 0; d < DMOD; ++d) m += s2v[d];
    m *= (1.f / DMOD);
    float va = 0.f;
    #pragma unroll
    for (int d = 0; d < DMOD; ++d) { const float z = s2v[d] - m; va += z * z; }
    va *= (1.f / DMOD);
    const float inv = rsqrtf(va + LN_EPS);
    #pragma unroll
    for (int d = 0; d < DMOD; ++d) ln[d] = (s2v[d] - m) * inv * g_norm[d] + b_norm[d];
  } else {
    #pragma unroll
    for (int d = 0; d < DMOD; ++d) ln[d] = 0.f;
  }
  __syncthreads();

  // ---- P11: u = adj @ ln ----
  float u[DMOD];
  #pragma unroll
  for (int i = 0; i < DMOD; ++i) {
    const float4* ar = (const float4*)&adjLDS[i][0];
    const float4 c0 = ar[0], c1 = ar[1], c2 = ar[2];
    const float2 c3 = ((const float2*)ar)[6];
    u[i] = c0.x * ln[0] + c0.y * ln[1] + c0.z * ln[2] + c0.w * ln[3]
         + c1.x * ln[4] + c1.y * ln[5] + c1.z * ln[6] + c1.w * ln[7]
         + c2.x * ln[8] + c2.y * ln[9] + c2.z * ln[10] + c2.w * ln[11]
         + c3.x * ln[12] + c3.y * ln[13];
  }
  if (act) {
    float4* ur = (float4*)&pool[half][l * 16];
    ur[0] = make_float4(u[0], u[1], u[2], u[3]);
    ur[1] = make_float4(u[4], u[5], u[6], u[7]);
    ur[2] = make_float4(u[8], u[9], u[10], u[11]);
    ((float2*)ur)[6] = make_float2(u[12], u[13]);
  }
  __syncthreads();

  // ---- P12: dy + write f (stride 448, bf16); pad written here too so each
  // f_out cacheline is assembled once ----
  if (live) {
    float acc[DMOD];
    #pragma unroll
    for (int i = 0; i < DMOD; ++i) acc[i] = 0.f;
    #pragma unroll 5
    for (int lp = 0; lp < LLEN; ++lp) {
      const float wd = W_dy[lp * LLEN + l];
      const float4* ur = (const float4*)&pool[half][lp * 16];
      const float4 a0 = ur[0], a1 = ur[1], a2 = ur[2];
      const float2 a3 = ((const float2*)ur)[6];
      acc[0] += a0.x * wd;  acc[1] += a0.y * wd;  acc[2]  += a0.z * wd;  acc[3]  += a0.w * wd;
      acc[4] += a1.x * wd;  acc[5] += a1.y * wd;  acc[6]  += a1.z * wd;  acc[7]  += a1.w * wd;
      acc[8] += a2.x * wd;  acc[9] += a2.y * wd;  acc[10] += a2.z * wd;  acc[11] += a2.w * wd;
      acc[12] += a3.x * wd; acc[13] += a3.y * wd;
    }
    const float bd = b_dy[l];
    u16* fo = f_out + (size_t)b * K1P + l;
    #pragma unroll
    for (int i = 0; i < DMOD; ++i)
      fo[i * LLEN] = f2bf(fmaxf(acc[i] + bd, 0.f));
    if (l < 28) f_out[(size_t)b * K1P + 420 + l] = (u16)0;
  }

}

// ========================= Weight prep (one-time-ish) =======================
__global__ void prep_kernel(const float* __restrict__ W1,
                            const float* __restrict__ Wres,
                            const float* __restrict__ W2,
                            u16* __restrict__ w1s,
                            u16* __restrict__ wrh, u16* __restrict__ wrl,
                            u16* __restrict__ w2h, u16* __restrict__ w2l)
{
  const int idx = blockIdx.x * 256 + threadIdx.x;
  if (idx < NREC_W1) {
    const int n1 = idx & 255;
    const int cs = idx >> 8;
    const int k0 = cs * 8;
    union { u16 h[8]; uint4 q; } R;
    #pragma unroll
    for (int i = 0; i < 8; ++i) {
      const int k = k0 + i;
      const float w = (k < 420) ? W1[k * 256 + n1] : 0.f;
      R.h[i] = f2bf(w);
    }
    *((uint4*)(w1s + (size_t)idx * 8)) = R.q;
  } else if (idx < NREC_W1 + NREC_WR) {
    const int id = idx - NREC_W1;
    const int row = id & 63;
    const int cs = id >> 6;
    const int k0 = cs * 8;
    union { u16 h[8]; uint4 q; } Rh, Rl;
    #pragma unroll
    for (int i = 0; i < 8; ++i) {
      const int k = k0 + i;
      const float w = (k < 420) ? Wres[k * 64 + row] : 0.f;
      const u16 hh = f2bf(w);
      Rh.h[i] = hh;
      Rl.h[i] = f2bf(w - bflo((u32)hh));
    }
    *((uint4*)(wrh + (size_t)id * 8)) = Rh.q;
    *((uint4*)(wrl + (size_t)id * 8)) = Rl.q;
  } else if (idx < NREC_W1 + NREC_WR + NREC_W2) {
    const int id = idx - NREC_W1 - NREC_WR;
    const int row = id & 63;
    const int cs = id >> 6;
    const int k0 = cs * 8;
    union { u16 h[8]; uint4 q; } Rh, Rl;
    #pragma unroll
    for (int i = 0; i < 8; ++i) {
      const float w = W2[(k0 + i) * 64 + row];
      const u16 hh = f2bf(w);
      Rh.h[i] = hh;
      Rl.h[i] = f2bf(w - bflo((u32)hh));
    }
    *((uint4*)(w2h + (size_t)id * 8)) = Rh.q;
    *((uint4*)(w2l + (size_t)id * 8)) = Rl.q;
  }
}

// ============================ MFMA MLP head =================================
__global__ __launch_bounds__(256, 3) void head_mfma(
    const u16* __restrict__ f, const u16* __restrict__ w1s,
    const u16* __restrict__ wrh, const u16* __restrict__ wrl,
    const u16* __restrict__ w2h, const u16* __restrict__ w2l,
    const float* __restrict__ b1, const float* __restrict__ b2,
    const float* __restrict__ bres, const float* __restrict__ g_ln,
    const float* __restrict__ b_ln, const float* __restrict__ W3,
    const float* __restrict__ b3, float* __restrict__ out, int Btot)
{
  const int lane = threadIdx.x & 63;
  const int wv   = threadIdx.x >> 6;
  const int g    = lane >> 4;       // k-slot / row-quadrant
  const int m    = lane & 15;       // sample within wave
  const int samp = blockIdx.x * 64 + wv * 16 + m;
  const int srow = (samp < Btot) ? samp : (Btot - 1);

  // f fragments: fr[c] = f[samp][32c + 8g .. +7]
  s16x8 fr[14];
  const u16* fp = f + (size_t)srow * K1P + g * 8;
  #pragma unroll
  for (int c = 0; c < 14; ++c)
    fr[c] = *((const s16x8*)(fp + 32 * c));

  const f32x4 zero4 = {0.f, 0.f, 0.f, 0.f};

  // ---- residual: r = f @ Wres (hi + lo); 4 independent nt chains ----
  f32x4 ac3[4] = {zero4, zero4, zero4, zero4};
  #pragma unroll
  for (int c = 0; c < 14; ++c) {
    const int bo = (c * 4 + g) * 512 + m * 8;
    #pragma unroll
    for (int nt = 0; nt < 4; ++nt) {
      const s16x8 ah = *((const s16x8*)(wrh + bo + nt * 128));
      ac3[nt] = __builtin_amdgcn_mfma_f32_16x16x32_bf16(ah, fr[c], ac3[nt], 0, 0, 0);
    }
    #pragma unroll
    for (int nt = 0; nt < 4; ++nt) {
      const s16x8 al = *((const s16x8*)(wrl + bo + nt * 128));
      ac3[nt] = __builtin_amdgcn_mfma_f32_16x16x32_bf16(al, fr[c], ac3[nt], 0, 0, 0);
    }
  }

  // ---- h = relu(f@W1 + b1) ; out2 = h @ W2 (hi + lo) ----
  f32x4 ac2[4] = {zero4, zero4, zero4, zero4};
  const int ap0 = ((g & 1) << 7) + (m << 2);
  const int ap1 = ap0 + 64;
  #pragma unroll 2
  for (int j = 0; j < 8; ++j) {
    f32x4 ha0 = zero4, ha1 = zero4, hb0 = zero4, hb1 = zero4;
    #pragma unroll
    for (int c = 0; c < 14; c += 2) {
      const int boA = (c * 4 + g) * 2048 + m * 8;
      const int boB = ((c + 1) * 4 + g) * 2048 + m * 8;
      const s16x8 wa0 = *((const s16x8*)(w1s + boA + (2 * j) * 128));
      const s16x8 wb0 = *((const s16x8*)(w1s + boA + (2 * j + 1) * 128));
      const s16x8 wa1 = *((const s16x8*)(w1s + boB + (2 * j) * 128));
      const s16x8 wb1 = *((const s16x8*)(w1s + boB + (2 * j + 1) * 128));
      ha0 = __builtin_amdgcn_mfma_f32_16x16x32_bf16(wa0, fr[c], ha0, 0, 0, 0);
      hb0 = __builtin_amdgcn_mfma_f32_16x16x32_bf16(wb0, fr[c], hb0, 0, 0, 0);
      ha1 = __builtin_amdgcn_mfma_f32_16x16x32_bf16(wa1, fr[c + 1], ha1, 0, 0, 0);
      hb1 = __builtin_amdgcn_mfma_f32_16x16x32_bf16(wb1, fr[c + 1], hb1, 0, 0, 0);
    }
    const f32x4 ha = ha0 + ha1;
    const f32x4 hb = hb0 + hb1;
    const int f0 = 32 * j + 4 * g;
    const float H00 = fmaxf(ha[0] + b1[f0 + 0], 0.f);
    const float H01 = fmaxf(ha[1] + b1[f0 + 1], 0.f);
    const float H02 = fmaxf(ha[2] + b1[f0 + 2], 0.f);
    const float H03 = fmaxf(ha[3] + b1[f0 + 3], 0.f);
    const float H10 = fmaxf(hb[0] + b1[f0 + 16], 0.f);
    const float H11 = fmaxf(hb[1] + b1[f0 + 17], 0.f);
    const float H12 = fmaxf(hb[2] + b1[f0 + 18], 0.f);
    const float H13 = fmaxf(hb[3] + b1[f0 + 19], 0.f);
    const u32 PK00 = pk2(H00, H01), PK01 = pk2(H10, H11);
    const u32 PK10 = pk2(H02, H03), PK11 = pk2(H12, H13);
    union { u32 u[4]; s16x8 v; } bb;
    {
      const u32 r0 = (u32)__builtin_amdgcn_ds_bpermute(ap0, (int)PK00);
      const u32 r1 = (u32)__builtin_amdgcn_ds_bpermute(ap0, (int)PK01);
      bb.u[0] = (g & 2) ? r1 : r0;
    }
    {
      const u32 r0 = (u32)__builtin_amdgcn_ds_bpermute(ap0, (int)PK10);
      const u32 r1 = (u32)__builtin_amdgcn_ds_bpermute(ap0, (int)PK11);
      bb.u[1] = (g & 2) ? r1 : r0;
    }
    {
      const u32 r0 = (u32)__builtin_amdgcn_ds_bpermute(ap1, (int)PK00);
      const u32 r1 = (u32)__builtin_amdgcn_ds_bpermute(ap1, (int)PK01);
      bb.u[2] = (g & 2) ? r1 : r0;
    }
    {
      const u32 r0 = (u32)__builtin_amdgcn_ds_bpermute(ap1, (int)PK10);
      const u32 r1 = (u32)__builtin_amdgcn_ds_bpermute(ap1, (int)PK11);
      bb.u[3] = (g & 2) ? r1 : r0;
    }
    const int bo2 = (j * 4 + g) * 512 + m * 8;
    #pragma unroll
    for (int nt = 0; nt < 4; ++nt) {
      const s16x8 a2h = *((const s16x8*)(w2h + bo2 + nt * 128));
      ac2[nt] = __builtin_amdgcn_mfma_f32_16x16x32_bf16(a2h, bb.v, ac2[nt], 0, 0, 0);
    }
    #pragma unroll
    for (int nt = 0; nt < 4; ++nt) {
      const s16x8 a2l = *((const s16x8*)(w2l + bo2 + nt * 128));
      ac2[nt] = __builtin_amdgcn_mfma_f32_16x16x32_bf16(a2l, bb.v, ac2[nt], 0, 0, 0);
    }
  }

  // ---- LayerNorm over 64 features + dot W3 ----
  float vals[4][4];
  float s1 = 0.f, sq = 0.f;
  #pragma unroll
  for (int nt = 0; nt < 4; ++nt) {
    #pragma unroll
    for (int r = 0; r < 4; ++r) {
      const int fe = 16 * nt + 4 * g + r;
      const float val = ac2[nt][r] + ac3[nt][r] + b2[fe] + bres[fe];
      vals[nt][r] = val; s1 += val; sq += val * val;
    }
  }
  s1 += __shfl_xor(s1, 16); s1 += __shfl_xor(s1, 32);
  sq += __shfl_xor(sq, 16); sq += __shfl_xor(sq, 32);
  const float mean = s1 * (1.f / 64.f);
  const float var  = sq * (1.f / 64.f) - mean * mean;
  const float inv  = rsqrtf(var + LN_EPS);
  float pr = 0.f;
  #pragma unroll
  for (int nt = 0; nt < 4; ++nt) {
    #pragma unroll
    for (int r = 0; r < 4; ++r) {
      const int fe = 16 * nt + 4 * g + r;
      const float n = (vals[nt][r] - mean) * inv * g_ln[fe] + b_ln[fe];
      pr += n * W3[fe];
    }
  }
  pr += __shfl_xor(pr, 16); pr += __shfl_xor(pr, 32);
  if (g == 0 && samp < Btot) out[samp] = pr + b3[0];
}

extern "C" void kernel_launch(void* const* d_in, const int* in_sizes, int n_in,
                              void* d_out, int out_size, void* d_ws, size_t ws_size,
                              hipStream_t stream) {
  const float* x        = (const float*)d_in[0];
  const float* W_emb    = (const float*)d_in[1];
  const float* b_emb    = (const float*)d_in[2];
  const float* Wq       = (const float*)d_in[3];
  const float* bq       = (const float*)d_in[4];
  const float* Wk       = (const float*)d_in[5];
  const float* bk       = (const float*)d_in[6];
  const float* Wv       = (const float*)d_in[7];
  const float* bv       = (const float*)d_in[8];
  const float* Wo       = (const float*)d_in[9];
  const float* bo       = (const float*)d_in[10];
  const float* W_ff1    = (const float*)d_in[11];
  const float* W_ff2    = (const float*)d_in[12];
  const float* g_norm   = (const float*)d_in[13];
  const float* b_norm   = (const float*)d_in[14];
  const float* W_dy     = (const float*)d_in[15];
  const float* b_dy     = (const float*)d_in[16];
  const float* channels = (const float*)d_in[17];
  const float* W1       = (const float*)d_in[18];
  const float* b1       = (const float*)d_in[19];
  const float* W2       = (const float*)d_in[20];
  const float* b2       = (const float*)d_in[21];
  const float* Wres     = (const float*)d_in[22];
  const float* bres     = (const float*)d_in[23];
  const float* g_ln     = (const float*)d_in[24];
  const float* b_ln     = (const float*)d_in[25];
  const float* W3       = (const float*)d_in[26];
  const float* b3       = (const float*)d_in[27];

  const int B = in_sizes[0] / (LLEN * DMOD);

  u16* fbuf = (u16*)d_ws;
  u16* w1s  = fbuf + (size_t)B * K1P;
  u16* wrh  = w1s + (size_t)NREC_W1 * 8;
  u16* wrl  = wrh + (size_t)NREC_WR * 8;
  u16* w2h  = wrl + (size_t)NREC_WR * 8;
  u16* w2l  = w2h + (size_t)NREC_W2 * 8;

  prep_kernel<<<78, 256, 0, stream>>>(W1, Wres, W2, w1s, wrh, wrl, w2h, w2l);

  const int nb_fe = (B + 1) / 2;
  fe_kernel<<<nb_fe, 64, 0, stream>>>(x, W_emb, b_emb, Wq, bq, Wk, bk, Wv, bv, Wo, bo,
                                      W_ff1, W_ff2, g_norm, b_norm, W_dy, b_dy, channels,
                                      fbuf, B);

  const int nb_h = (B + 63) / 64;
  head_mfma<<<nb_h, 256, 0, stream>>>(fbuf, w1s, wrh, wrl, w2h, w2l,
                                      b1, b2, bres, g_ln, b_ln, W3, b3,
                                      (float*)d_out, B);
}

// Round 4
// 522.488 us; speedup vs baseline: 1.2895x; 1.2855x over previous
//
#include <hip/hip_runtime.h>
#include <hip/hip_bf16.h>
#include <math.h>

#define LLEN 30
#define DMOD 14
#define NH 8
#define NFF 50
#define LN_EPS 1e-5f
#define K1P 448           // padded inner dim for f (420 -> 448 = 14*32)
#define NREC_W1 14336     // 14 chunks * 4 slots * 256 rows
#define NREC_WR 3584      // 14 chunks * 4 slots * 64 rows
#define NREC_W2 2048      // 8 chunks * 4 slots * 64 rows
#define NPREP_W (NREC_W1 + NREC_WR + NREC_W2)   // 19968
#define NF1T 700          // W_ff1T  (50x14 fp32)
#define NEMT 588          // W_embT  ([c][k][o] fp32)
#define NDYT 900          // W_dyT   (30x30 fp32)

typedef unsigned short u16;
typedef unsigned int u32;
typedef __attribute__((ext_vector_type(8))) short s16x8;   // 8 bf16 = 4 VGPRs (MFMA A/B frag)
typedef __attribute__((ext_vector_type(4))) float f32x4;   // MFMA C/D frag

__device__ __forceinline__ float bflo(u32 v) {
  union { u32 u; float f; } w; w.u = v << 16; return w.f;
}
__device__ __forceinline__ u16 f2bf(float f) {
  union { float f; u32 u; } w; w.f = f;
  u32 x = w.u;
  x = (x + 0x7FFFu + ((x >> 16) & 1u)) >> 16;
  return (u16)x;
}
__device__ __forceinline__ u32 pk2(float lo, float hi) {
  return (u32)f2bf(lo) | ((u32)f2bf(hi) << 16);
}
// paired fp32 fma -> v_pk_fma_f32 on CDNA
__device__ __forceinline__ float2 f2fma(float2 a, float2 b, float2 c) {
  float2 r; r.x = fmaf(a.x, b.x, c.x); r.y = fmaf(a.y, b.y, c.y); return r;
}

// Branch-free GELU: erf via Abramowitz-Stegun 7.1.26 (max abs err ~1.5e-7).
__device__ __forceinline__ float gelu_fast(float a) {
  const float z  = fabsf(a) * 0.70710678118654752f;
  const float t  = __builtin_amdgcn_rcpf(1.f + 0.3275911f * z);
  const float p  = t * (0.254829592f + t * (-0.284496736f +
                   t * (1.421413741f + t * (-1.453152027f + t * 1.061405429f))));
  float e = 1.f - p * __expf(-z * z);
  e = copysignf(e, a);
  return 0.5f * a * (1.f + e);
}

// Exact replicate-pad 25-tap MA removal on one contiguous 30-float LDS row.
__device__ __forceinline__ void decomp_row_lds(float* row) {
  float xv[30];
  const float2* r2 = (const float2*)row;
  #pragma unroll
  for (int j = 0; j < 15; ++j) { float2 w = r2[j]; xv[2*j] = w.x; xv[2*j+1] = w.y; }
  float2* w2 = (float2*)row;
  float ws = 13.f * xv[0];
  #pragma unroll
  for (int j = 1; j <= 12; ++j) ws += xv[j];
  float rprev = xv[0] - ws * (1.f / 25.f);
  #pragma unroll
  for (int jj = 1; jj < 30; ++jj) {
    const int hi = (jj + 12 > 29) ? 29 : jj + 12;
    const int lo = (jj - 13 < 0) ? 0 : jj - 13;
    ws += xv[hi] - xv[lo];
    const float r = xv[jj] - ws * (1.f / 25.f);
    if (jj & 1) { w2[jj >> 1] = make_float2(rprev, r); } else { rprev = r; }
  }
}

// ============================ Front-end kernel ==============================
// VALU-issue-bound: all inner d-loops run as float2 pairs (v_pk_fma_f32),
// fed by prep-transposed weights (W_ff1T, W_embT, W_dyT) for contiguity.
__global__ __launch_bounds__(64, 3) void fe_kernel(
    const float* __restrict__ x,
    const float* __restrict__ b_emb,
    const float* __restrict__ Wq, const float* __restrict__ bq,
    const float* __restrict__ Wk, const float* __restrict__ bk,
    const float* __restrict__ Wv, const float* __restrict__ bv,
    const float* __restrict__ Wo, const float* __restrict__ bo,
    const float* __restrict__ W_ff2,
    const float* __restrict__ g_norm, const float* __restrict__ b_norm,
    const float* __restrict__ b_dy,
    const float* __restrict__ channels,
    const float* __restrict__ wff1T, const float* __restrict__ wembT,
    const float* __restrict__ wdyT,
    u16* __restrict__ f_out, int Btot)
{
  const int t    = threadIdx.x;
  const int half = t >> 5;
  const int l    = t & 31;
  const int base = half << 5;
  const bool act = (l < LLEN);
  const int b    = blockIdx.x * 2 + half;
  const bool live = act && (b < Btot);

  __shared__ float pool[2][600];
  __shared__ float adjLDS[DMOD][16];
  __shared__ float MV[2][32];
  __shared__ float TW[2][4];
  __shared__ int   TD[2][4];

  // ---- P0: load x; lanes t<14 compute adj ----
  float xr[DMOD];
  if (live) {
    const float2* xp2 = (const float2*)(x + (size_t)b * 420 + l * DMOD);
    #pragma unroll
    for (int j = 0; j < 7; ++j) { float2 v = xp2[j]; xr[2*j] = v.x; xr[2*j+1] = v.y; }
  } else {
    #pragma unroll
    for (int d = 0; d < DMOD; ++d) xr[d] = 0.f;
  }
  if (t < DMOD) {
    float row[DMOD]; float m = -1e30f;
    #pragma unroll
    for (int j = 0; j < DMOD; ++j) { row[j] = channels[t * DMOD + j]; m = fmaxf(m, row[j]); }
    float s = 0.f;
    #pragma unroll
    for (int j = 0; j < DMOD; ++j) { row[j] = __expf(row[j] - m); s += row[j]; }
    const float inv = 1.f / s;
    #pragma unroll
    for (int j = 0; j < DMOD; ++j) adjLDS[t][j] = row[j] * inv;
  }

  // ---- P1: conv1d embed (packed) ----
  float2 xe2[7];
  {
    const float2* be2 = (const float2*)b_emb;
    #pragma unroll
    for (int o = 0; o < 7; ++o) xe2[o] = be2[o];
  }
  #pragma unroll
  for (int c = 0; c < DMOD; ++c) {
    float xm = __shfl(xr[c], t - 1);
    float xp = __shfl(xr[c], t + 1);
    xm = (l == 0) ? 0.f : xm;
    xp = (l >= LLEN - 1) ? 0.f : xp;
    const float xc = xr[c];
    const float2* w0  = (const float2*)(wembT + c * 42);
    const float2* w1p = (const float2*)(wembT + c * 42 + 14);
    const float2* w2p = (const float2*)(wembT + c * 42 + 28);
    const float2 m2 = make_float2(xm, xm);
    const float2 c2 = make_float2(xc, xc);
    const float2 p2 = make_float2(xp, xp);
    #pragma unroll
    for (int o = 0; o < 7; ++o)
      xe2[o] = f2fma(m2, w0[o], f2fma(c2, w1p[o], f2fma(p2, w2p[o], xe2[o])));
  }

  // ---- P2: q,k,v (packed; W rows contiguous over h) ----
  float2 q2[4], k2[4], v2[4];
  {
    const float2* bq2 = (const float2*)bq;
    const float2* bk2 = (const float2*)bk;
    const float2* bv2 = (const float2*)bv;
    #pragma unroll
    for (int jj = 0; jj < 4; ++jj) { q2[jj] = bq2[jj]; k2[jj] = bk2[jj]; v2[jj] = bv2[jj]; }
  }
  #pragma unroll
  for (int d = 0; d < DMOD; ++d) {
    const float e = (d & 1) ? xe2[d >> 1].y : xe2[d >> 1].x;
    const float2 e2 = make_float2(e, e);
    const float2* wq2 = (const float2*)(Wq + d * NH);
    const float2* wk2 = (const float2*)(Wk + d * NH);
    const float2* wv2 = (const float2*)(Wv + d * NH);
    #pragma unroll
    for (int jj = 0; jj < 4; ++jj) {
      q2[jj] = f2fma(e2, wq2[jj], q2[jj]);
      k2[jj] = f2fma(e2, wk2[jj], k2[jj]);
      v2[jj] = f2fma(e2, wv2[jj], v2[jj]);
    }
  }

  // ---- P3: autocorr ----
  if (act) {
    float2* qr = (float2*)&pool[half][l * 10];
    qr[0] = q2[0]; qr[1] = q2[1]; qr[2] = q2[2]; qr[3] = q2[3];
    float2* kr = (float2*)&pool[half][300 + l * 10];
    kr[0] = k2[0]; kr[1] = k2[1]; kr[2] = k2[2]; kr[3] = k2[3];
  }
  __syncthreads();
  if (act) {
    float2 aa = make_float2(0.f, 0.f), ab = make_float2(0.f, 0.f);
    #pragma unroll 5
    for (int s = 0; s < LLEN; ++s) {
      int rq = l + s; if (rq >= LLEN) rq -= LLEN;
      const float2* qa = (const float2*)&pool[half][rq * 10];
      const float2* ka = (const float2*)&pool[half][300 + s * 10];
      aa = f2fma(qa[0], ka[0], aa); ab = f2fma(qa[1], ka[1], ab);
      aa = f2fma(qa[2], ka[2], aa); ab = f2fma(qa[3], ka[3], ab);
    }
    MV[half][l] = (aa.x + aa.y + ab.x + ab.y) * (1.f / NH);
  }
  __syncthreads();

  // ---- P4: top-3 + softmax ----
  if (l == 0) {
    float v1 = -1e30f, v2v = -1e30f, v3 = -1e30f; int i1 = 0, i2 = 0, i3 = 0;
    for (int i = 0; i < LLEN; ++i) {
      const float vv = MV[half][i];
      if (vv > v1)       { v3 = v2v; i3 = i2; v2v = v1; i2 = i1; v1 = vv; i1 = i; }
      else if (vv > v2v) { v3 = v2v; i3 = i2; v2v = vv; i2 = i; }
      else if (vv > v3)  { v3 = vv; i3 = i; }
    }
    const float e2 = __expf(v2v - v1), e3 = __expf(v3 - v1);
    const float inv = 1.f / (1.f + e2 + e3);
    TW[half][0] = inv; TW[half][1] = e2 * inv; TW[half][2] = e3 * inv;
    TD[half][0] = i1; TD[half][1] = i2; TD[half][2] = i3;
  }
  __syncthreads();

  // ---- P5: weighted circular gather ----
  float agg[NH];
  #pragma unroll
  for (int h = 0; h < NH; ++h) agg[h] = 0.f;
  #pragma unroll
  for (int kk = 0; kk < 3; ++kk) {
    const float w = TW[half][kk];
    const int dd = TD[half][kk];
    int sidx = l + dd; if (sidx >= LLEN) sidx -= LLEN;
    const int src = base + sidx;
    #pragma unroll
    for (int h = 0; h < NH; ++h) {
      const float vh = (h & 1) ? v2[h >> 1].y : v2[h >> 1].x;
      agg[h] += w * __shfl(vh, src);
    }
  }

  // ---- P6: out-proj + residual (packed; Wo rows contiguous over d) ----
  {
    const float2* bo2 = (const float2*)bo;
    #pragma unroll
    for (int d2 = 0; d2 < 7; ++d2) {
      xe2[d2].x += bo2[d2].x; xe2[d2].y += bo2[d2].y;
    }
  }
  #pragma unroll
  for (int h = 0; h < NH; ++h) {
    const float2 ag = make_float2(agg[h], agg[h]);
    const float2* wo2 = (const float2*)(Wo + h * DMOD);
    #pragma unroll
    for (int d2 = 0; d2 < 7; ++d2) xe2[d2] = f2fma(ag, wo2[d2], xe2[d2]);
  }
  __syncthreads();

  // ---- P7: decomp #1 ----
  if (act) {
    #pragma unroll
    for (int d = 0; d < DMOD; ++d)
      pool[half][d * LLEN + l] = (d & 1) ? xe2[d >> 1].y : xe2[d >> 1].x;
  }
  __syncthreads();
  if (l < DMOD) decomp_row_lds(&pool[half][l * LLEN]);
  __syncthreads();
  float2 s1p[7];
  if (act) {
    #pragma unroll
    for (int j = 0; j < 7; ++j)
      s1p[j] = make_float2(pool[half][(2 * j) * LLEN + l], pool[half][(2 * j + 1) * LLEN + l]);
  } else {
    #pragma unroll
    for (int j = 0; j < 7; ++j) s1p[j] = make_float2(0.f, 0.f);
  }
  __syncthreads();

  // ---- P8: FFN (packed; W_ff1T rows contiguous) ----
  float2 y2[7];
  #pragma unroll
  for (int j = 0; j < 7; ++j) y2[j] = make_float2(0.f, 0.f);
  #pragma unroll 5
  for (int ff = 0; ff < NFF; ++ff) {
    const float2* w1r = (const float2*)(wff1T + ff * DMOD);
    float2 a2 = make_float2(0.f, 0.f), c2 = make_float2(0.f, 0.f);
    a2 = f2fma(s1p[0], w1r[0], a2); c2 = f2fma(s1p[1], w1r[1], c2);
    a2 = f2fma(s1p[2], w1r[2], a2); c2 = f2fma(s1p[3], w1r[3], c2);
    a2 = f2fma(s1p[4], w1r[4], a2); c2 = f2fma(s1p[5], w1r[5], c2);
    a2 = f2fma(s1p[6], w1r[6], a2);
    const float a = a2.x + a2.y + c2.x + c2.y;
    const float gl = gelu_fast(a);
    const float2 g2 = make_float2(gl, gl);
    const float2* w2r = (const float2*)(W_ff2 + ff * DMOD);
    #pragma unroll
    for (int j = 0; j < 7; ++j) y2[j] = f2fma(g2, w2r[j], y2[j]);
  }

  // ---- P9: decomp #2 ----
  if (act) {
    #pragma unroll
    for (int j = 0; j < 7; ++j) {
      pool[half][(2 * j) * LLEN + l]     = s1p[j].x + y2[j].x;
      pool[half][(2 * j + 1) * LLEN + l] = s1p[j].y + y2[j].y;
    }
  }
  __syncthreads();
  if (l < DMOD) decomp_row_lds(&pool[half][l * LLEN]);
  __syncthreads();

  // ---- P10: LayerNorm over D ----
  float2 ln2[7];
  if (act) {
    float s2v[DMOD];
    #pragma unroll
    for (int d = 0; d < DMOD; ++d) s2v[d] = pool[half][d * LLEN + l];
    float m = 0.f;
    #pragma unroll
    for (int d = 0; d < DMOD; ++d) m += s2v[d];
    m *= (1.f / DMOD);
    float va = 0.f;
    #pragma unroll
    for (int d = 0; d < DMOD; ++d) { const float z = s2v[d] - m; va += z * z; }
    va *= (1.f / DMOD);
    const float inv = rsqrtf(va + LN_EPS);
    #pragma unroll
    for (int j = 0; j < 7; ++j) {
      const float za = (s2v[2 * j] - m) * inv;
      const float zb = (s2v[2 * j + 1] - m) * inv;
      ln2[j] = make_float2(fmaf(za, g_norm[2 * j], b_norm[2 * j]),
                           fmaf(zb, g_norm[2 * j + 1], b_norm[2 * j + 1]));
    }
  } else {
    #pragma unroll
    for (int j = 0; j < 7; ++j) ln2[j] = make_float2(0.f, 0.f);
  }
  __syncthreads();

  // ---- P11: u = adj @ ln (packed) ----
  float u[DMOD];
  #pragma unroll
  for (int i = 0; i < DMOD; ++i) {
    const float4* ar = (const float4*)&adjLDS[i][0];
    const float4 c0 = ar[0], c1 = ar[1], c2 = ar[2];
    const float2 c3 = ((const float2*)ar)[6];
    float2 ua = make_float2(0.f, 0.f), ub = make_float2(0.f, 0.f);
    ua = f2fma(make_float2(c0.x, c0.y), ln2[0], ua);
    ub = f2fma(make_float2(c0.z, c0.w), ln2[1], ub);
    ua = f2fma(make_float2(c1.x, c1.y), ln2[2], ua);
    ub = f2fma(make_float2(c1.z, c1.w), ln2[3], ub);
    ua = f2fma(make_float2(c2.x, c2.y), ln2[4], ua);
    ub = f2fma(make_float2(c2.z, c2.w), ln2[5], ub);
    ua = f2fma(c3, ln2[6], ua);
    u[i] = ua.x + ua.y + ub.x + ub.y;
  }
  if (act) {
    float4* ur = (float4*)&pool[half][l * 16];
    ur[0] = make_float4(u[0], u[1], u[2], u[3]);
    ur[1] = make_float4(u[4], u[5], u[6], u[7]);
    ur[2] = make_float4(u[8], u[9], u[10], u[11]);
    ((float2*)ur)[6] = make_float2(u[12], u[13]);
  }
  __syncthreads();

  // ---- P12: dy + write f (stride 448, bf16); packed accumulate ----
  if (live) {
    float2 acc2[7];
    #pragma unroll
    for (int j = 0; j < 7; ++j) acc2[j] = make_float2(0.f, 0.f);
    const float* wcol = wdyT + l * LLEN;   // contiguous W_dy column for lane l
    #pragma unroll 5
    for (int lp = 0; lp < LLEN; ++lp) {
      const float wd = wcol[lp];
      const float2 w2v = make_float2(wd, wd);
      const float4* ur = (const float4*)&pool[half][lp * 16];
      const float4 a0 = ur[0], a1 = ur[1], a2 = ur[2];
      const float2 a3 = ((const float2*)ur)[6];
      acc2[0] = f2fma(w2v, make_float2(a0.x, a0.y), acc2[0]);
      acc2[1] = f2fma(w2v, make_float2(a0.z, a0.w), acc2[1]);
      acc2[2] = f2fma(w2v, make_float2(a1.x, a1.y), acc2[2]);
      acc2[3] = f2fma(w2v, make_float2(a1.z, a1.w), acc2[3]);
      acc2[4] = f2fma(w2v, make_float2(a2.x, a2.y), acc2[4]);
      acc2[5] = f2fma(w2v, make_float2(a2.z, a2.w), acc2[5]);
      acc2[6] = f2fma(w2v, a3, acc2[6]);
    }
    const float bd = b_dy[l];
    u16* fo = f_out + (size_t)b * K1P + l;
    #pragma unroll
    for (int i = 0; i < DMOD; ++i) {
      const float av = (i & 1) ? acc2[i >> 1].y : acc2[i >> 1].x;
      fo[i * LLEN] = f2bf(fmaxf(av + bd, 0.f));
    }
    if (l < 28) f_out[(size_t)b * K1P + 420 + l] = (u16)0;
  }
}

// ========================= Weight prep (one-time-ish) =======================
__global__ void prep_kernel(const float* __restrict__ W1,
                            const float* __restrict__ Wres,
                            const float* __restrict__ W2,
                            const float* __restrict__ W_ff1,
                            const float* __restrict__ W_emb,
                            const float* __restrict__ W_dy,
                            u16* __restrict__ w1s,
                            u16* __restrict__ wrh, u16* __restrict__ wrl,
                            u16* __restrict__ w2h, u16* __restrict__ w2l,
                            float* __restrict__ wff1T, float* __restrict__ wembT,
                            float* __restrict__ wdyT)
{
  const int idx = blockIdx.x * 256 + threadIdx.x;
  if (idx < NREC_W1) {
    const int n1 = idx & 255;
    const int cs = idx >> 8;
    const int k0 = cs * 8;
    union { u16 h[8]; uint4 q; } R;
    #pragma unroll
    for (int i = 0; i < 8; ++i) {
      const int k = k0 + i;
      const float w = (k < 420) ? W1[k * 256 + n1] : 0.f;
      R.h[i] = f2bf(w);
    }
    *((uint4*)(w1s + (size_t)idx * 8)) = R.q;
  } else if (idx < NREC_W1 + NREC_WR) {
    const int id = idx - NREC_W1;
    const int row = id & 63;
    const int cs = id >> 6;
    const int k0 = cs * 8;
    union { u16 h[8]; uint4 q; } Rh, Rl;
    #pragma unroll
    for (int i = 0; i < 8; ++i) {
      const int k = k0 + i;
      const float w = (k < 420) ? Wres[k * 64 + row] : 0.f;
      const u16 hh = f2bf(w);
      Rh.h[i] = hh;
      Rl.h[i] = f2bf(w - bflo((u32)hh));
    }
    *((uint4*)(wrh + (size_t)id * 8)) = Rh.q;
    *((uint4*)(wrl + (size_t)id * 8)) = Rl.q;
  } else if (idx < NPREP_W) {
    const int id = idx - NREC_W1 - NREC_WR;
    const int row = id & 63;
    const int cs = id >> 6;
    const int k0 = cs * 8;
    union { u16 h[8]; uint4 q; } Rh, Rl;
    #pragma unroll
    for (int i = 0; i < 8; ++i) {
      const float w = W2[(k0 + i) * 64 + row];
      const u16 hh = f2bf(w);
      Rh.h[i] = hh;
      Rl.h[i] = f2bf(w - bflo((u32)hh));
    }
    *((uint4*)(w2h + (size_t)id * 8)) = Rh.q;
    *((uint4*)(w2l + (size_t)id * 8)) = Rl.q;
  } else if (idx < NPREP_W + NF1T) {
    const int of = idx - NPREP_W;
    const int ff = of / DMOD;
    const int d  = of - ff * DMOD;
    wff1T[of] = W_ff1[d * NFF + ff];
  } else if (idx < NPREP_W + NF1T + NEMT) {
    const int of = idx - NPREP_W - NF1T;
    const int c  = of / 42;
    const int r  = of - c * 42;
    const int kk = r / DMOD;
    const int o  = r - kk * DMOD;
    wembT[of] = W_emb[o * 42 + c * 3 + kk];
  } else if (idx < NPREP_W + NF1T + NEMT + NDYT) {
    const int of = idx - NPREP_W - NF1T - NEMT;
    const int l  = of / LLEN;
    const int lp = of - l * LLEN;
    wdyT[of] = W_dy[lp * LLEN + l];
  }
}

// ============================ MFMA MLP head =================================
// Weight tiles staged to LDS once per BLOCK (4 waves share), with T14
// issue-early/write-late overlap. LDS layout pads each record-group by
// +8 u16 so the 4 g-groups hit different bank sets.
//   Phase A (Wres, 14 c-steps): tile = 512 recs (hi 0..255 @ r*8+(r>>6)*8,
//     lo same +2176).
//   Phase B (W1+W2, 8 j-steps): W1 tile = 1792 recs @ u*8+(u>>5)*8;
//     W2 tile = 512 recs at base 14848 (same sub-layout as phase A).
__global__ __launch_bounds__(256, 2) void head_mfma(
    const u16* __restrict__ f, const u16* __restrict__ w1s,
    const u16* __restrict__ wrh, const u16* __restrict__ wrl,
    const u16* __restrict__ w2h, const u16* __restrict__ w2l,
    const float* __restrict__ b1, const float* __restrict__ b2,
    const float* __restrict__ bres, const float* __restrict__ g_ln,
    const float* __restrict__ b_ln, const float* __restrict__ W3,
    const float* __restrict__ b3, float* __restrict__ out, int Btot)
{
  const int t    = threadIdx.x;
  const int lane = t & 63;
  const int wv   = t >> 6;
  const int g    = lane >> 4;       // k-slot / row-quadrant
  const int m    = lane & 15;       // sample within wave
  const int samp = blockIdx.x * 64 + wv * 16 + m;
  const int srow = (samp < Btot) ? samp : (Btot - 1);

  __shared__ u16 wlds[19200];       // 38.4 KB
  uint4* w4 = (uint4*)wlds;
  const int to = t + (t >> 6);      // padded local offset for 256-rec tiles

  // f fragments: fr[c] = f[samp][32c + 8g .. +7]
  s16x8 fr[14];
  const u16* fp = f + (size_t)srow * K1P + g * 8;
  #pragma unroll
  for (int c = 0; c < 14; ++c)
    fr[c] = *((const s16x8*)(fp + 32 * c));

  const f32x4 zero4 = {0.f, 0.f, 0.f, 0.f};
  const int rbase = g * 520 + m * 8;   // lane's read base within a 256-rec tile

  // ---- Phase A: residual r = f @ Wres (hi + lo), Wres staged per-c ----
  {
    const uint4 ra = ((const uint4*)wrh)[t];
    const uint4 rb = ((const uint4*)wrl)[t];
    w4[to] = ra; w4[272 + to] = rb;
  }
  __syncthreads();

  f32x4 ac3[4] = {zero4, zero4, zero4, zero4};
  #pragma unroll
  for (int c = 0; c < 14; ++c) {
    uint4 na, nb;
    if (c < 13) {
      na = ((const uint4*)wrh)[(c + 1) * 256 + t];
      nb = ((const uint4*)wrl)[(c + 1) * 256 + t];
    }
    #pragma unroll
    for (int nt = 0; nt < 4; ++nt) {
      const s16x8 ah = *(const s16x8*)&wlds[rbase + nt * 128];
      ac3[nt] = __builtin_amdgcn_mfma_f32_16x16x32_bf16(ah, fr[c], ac3[nt], 0, 0, 0);
    }
    #pragma unroll
    for (int nt = 0; nt < 4; ++nt) {
      const s16x8 al = *(const s16x8*)&wlds[2176 + rbase + nt * 128];
      ac3[nt] = __builtin_amdgcn_mfma_f32_16x16x32_bf16(al, fr[c], ac3[nt], 0, 0, 0);
    }
    __syncthreads();
    if (c < 13) { w4[to] = na; w4[272 + to] = nb; }
    __syncthreads();
  }

  // ---- Phase B: h = relu(f@W1 + b1) ; out2 = h @ W2 (hi + lo) ----
  f32x4 ac2[4] = {zero4, zero4, zero4, zero4};
  const int ap0 = ((g & 1) << 7) + (m << 2);
  const int ap1 = ap0 + 64;

  // prologue: stage j=0 tiles
  {
    #pragma unroll
    for (int i = 0; i < 7; ++i) {
      const int u = t + i * 256;
      const uint4 rv = ((const uint4*)w1s)[(u >> 5) * 256 + (u & 31)];
      w4[u + (u >> 5)] = rv;
    }
    const uint4 h2 = ((const uint4*)w2h)[t];
    const uint4 l2 = ((const uint4*)w2l)[t];
    w4[1856 + to] = h2;
    w4[1856 + 272 + to] = l2;
  }
  __syncthreads();

  #pragma unroll 1
  for (int j = 0; j < 8; ++j) {
    uint4 n1[7], nh2, nl2;
    if (j < 7) {
      #pragma unroll
      for (int i = 0; i < 7; ++i) {
        const int u = t + i * 256;
        n1[i] = ((const uint4*)w1s)[(u >> 5) * 256 + 32 * (j + 1) + (u & 31)];
      }
      nh2 = ((const uint4*)w2h)[(j + 1) * 256 + t];
      nl2 = ((const uint4*)w2l)[(j + 1) * 256 + t];
    }
    // W1 MFMAs from LDS (split accumulate chains)
    f32x4 ha0 = zero4, ha1 = zero4, hb0 = zero4, hb1 = zero4;
    #pragma unroll
    for (int c = 0; c < 14; c += 2) {
      const int A0 = (4 * c + g) * 264 + m * 8;
      const int A1 = (4 * (c + 1) + g) * 264 + m * 8;
      const s16x8 wa0 = *(const s16x8*)&wlds[A0];
      const s16x8 wb0 = *(const s16x8*)&wlds[A0 + 128];
      const s16x8 wa1 = *(const s16x8*)&wlds[A1];
      const s16x8 wb1 = *(const s16x8*)&wlds[A1 + 128];
      ha0 = __builtin_amdgcn_mfma_f32_16x16x32_bf16(wa0, fr[c], ha0, 0, 0, 0);
      hb0 = __builtin_amdgcn_mfma_f32_16x16x32_bf16(wb0, fr[c], hb0, 0, 0, 0);
      ha1 = __builtin_amdgcn_mfma_f32_16x16x32_bf16(wa1, fr[c + 1], ha1, 0, 0, 0);
      hb1 = __builtin_amdgcn_mfma_f32_16x16x32_bf16(wb1, fr[c + 1], hb1, 0, 0, 0);
    }
    const f32x4 ha = ha0 + ha1;
    const f32x4 hb = hb0 + hb1;
    const int f0 = 32 * j + 4 * g;
    const float H00 = fmaxf(ha[0] + b1[f0 + 0], 0.f);
    const float H01 = fmaxf(ha[1] + b1[f0 + 1], 0.f);
    const float H02 = fmaxf(ha[2] + b1[f0 + 2], 0.f);
    const float H03 = fmaxf(ha[3] + b1[f0 + 3], 0.f);
    const float H10 = fmaxf(hb[0] + b1[f0 + 16], 0.f);
    const float H11 = fmaxf(hb[1] + b1[f0 + 17], 0.f);
    const float H12 = fmaxf(hb[2] + b1[f0 + 18], 0.f);
    const float H13 = fmaxf(hb[3] + b1[f0 + 19], 0.f);
    const u32 PK00 = pk2(H00, H01), PK01 = pk2(H10, H11);
    const u32 PK10 = pk2(H02, H03), PK11 = pk2(H12, H13);
    union { u32 u[4]; s16x8 v; } bb;
    {
      const u32 r0 = (u32)__builtin_amdgcn_ds_bpermute(ap0, (int)PK00);
      const u32 r1 = (u32)__builtin_amdgcn_ds_bpermute(ap0, (int)PK01);
      bb.u[0] = (g & 2) ? r1 : r0;
    }
    {
      const u32 r0 = (u32)__builtin_amdgcn_ds_bpermute(ap0, (int)PK10);
      const u32 r1 = (u32)__builtin_amdgcn_ds_bpermute(ap0, (int)PK11);
      bb.u[1] = (g & 2) ? r1 : r0;
    }
    {
      const u32 r0 = (u32)__builtin_amdgcn_ds_bpermute(ap1, (int)PK00);
      const u32 r1 = (u32)__builtin_amdgcn_ds_bpermute(ap1, (int)PK01);
      bb.u[2] = (g & 2) ? r1 : r0;
    }
    {
      const u32 r0 = (u32)__builtin_amdgcn_ds_bpermute(ap1, (int)PK10);
      const u32 r1 = (u32)__builtin_amdgcn_ds_bpermute(ap1, (int)PK11);
      bb.u[3] = (g & 2) ? r1 : r0;
    }
    // W2 MFMAs from LDS
    #pragma unroll
    for (int nt = 0; nt < 4; ++nt) {
      const s16x8 a2h = *(const s16x8*)&wlds[14848 + rbase + nt * 128];
      ac2[nt] = __builtin_amdgcn_mfma_f32_16x16x32_bf16(a2h, bb.v, ac2[nt], 0, 0, 0);
    }
    #pragma unroll
    for (int nt = 0; nt < 4; ++nt) {
      const s16x8 a2l = *(const s16x8*)&wlds[14848 + 2176 + rbase + nt * 128];
      ac2[nt] = __builtin_amdgcn_mfma_f32_16x16x32_bf16(a2l, bb.v, ac2[nt], 0, 0, 0);
    }
    __syncthreads();
    if (j < 7) {
      #pragma unroll
      for (int i = 0; i < 7; ++i) {
        const int u = t + i * 256;
        w4[u + (u >> 5)] = n1[i];
      }
      w4[1856 + to] = nh2;
      w4[1856 + 272 + to] = nl2;
    }
    __syncthreads();
  }

  // ---- LayerNorm over 64 features + dot W3 ----
  float vals[4][4];
  float s1 = 0.f, sq = 0.f;
  #pragma unroll
  for (int nt = 0; nt < 4; ++nt) {
    #pragma unroll
    for (int r = 0; r < 4; ++r) {
      const int fe = 16 * nt + 4 * g + r;
      const float val = ac2[nt][r] + ac3[nt][r] + b2[fe] + bres[fe];
      vals[nt][r] = val; s1 += val; sq += val * val;
    }
  }
  s1 += __shfl_xor(s1, 16); s1 += __shfl_xor(s1, 32);
  sq += __shfl_xor(sq, 16); sq += __shfl_xor(sq, 32);
  const float mean = s1 * (1.f / 64.f);
  const float var  = sq * (1.f / 64.f) - mean * mean;
  const float inv  = rsqrtf(var + LN_EPS);
  float pr = 0.f;
  #pragma unroll
  for (int nt = 0; nt < 4; ++nt) {
    #pragma unroll
    for (int r = 0; r < 4; ++r) {
      const int fe = 16 * nt + 4 * g + r;
      const float n = (vals[nt][r] - mean) * inv * g_ln[fe] + b_ln[fe];
      pr += n * W3[fe];
    }
  }
  pr += __shfl_xor(pr, 16); pr += __shfl_xor(pr, 32);
  if (g == 0 && samp < Btot) out[samp] = pr + b3[0];
}

extern "C" void kernel_launch(void* const* d_in, const int* in_sizes, int n_in,
                              void* d_out, int out_size, void* d_ws, size_t ws_size,
                              hipStream_t stream) {
  const float* x        = (const float*)d_in[0];
  const float* W_emb    = (const float*)d_in[1];
  const float* b_emb    = (const float*)d_in[2];
  const float* Wq       = (const float*)d_in[3];
  const float* bq       = (const float*)d_in[4];
  const float* Wk       = (const float*)d_in[5];
  const float* bk       = (const float*)d_in[6];
  const float* Wv       = (const float*)d_in[7];
  const float* bv       = (const float*)d_in[8];
  const float* Wo       = (const float*)d_in[9];
  const float* bo       = (const float*)d_in[10];
  const float* W_ff1    = (const float*)d_in[11];
  const float* W_ff2    = (const float*)d_in[12];
  const float* g_norm   = (const float*)d_in[13];
  const float* b_norm   = (const float*)d_in[14];
  const float* W_dy     = (const float*)d_in[15];
  const float* b_dy     = (const float*)d_in[16];
  const float* channels = (const float*)d_in[17];
  const float* W1       = (const float*)d_in[18];
  const float* b1       = (const float*)d_in[19];
  const float* W2       = (const float*)d_in[20];
  const float* b2       = (const float*)d_in[21];
  const float* Wres     = (const float*)d_in[22];
  const float* bres     = (const float*)d_in[23];
  const float* g_ln     = (const float*)d_in[24];
  const float* b_ln     = (const float*)d_in[25];
  const float* W3       = (const float*)d_in[26];
  const float* b3       = (const float*)d_in[27];

  const int B = in_sizes[0] / (LLEN * DMOD);

  // workspace (u16 units then fp32 section, all 16B aligned):
  u16* fbuf = (u16*)d_ws;
  u16* w1s  = fbuf + (size_t)B * K1P;
  u16* wrh  = w1s + (size_t)NREC_W1 * 8;
  u16* wrl  = wrh + (size_t)NREC_WR * 8;
  u16* w2h  = wrl + (size_t)NREC_WR * 8;
  u16* w2l  = w2h + (size_t)NREC_W2 * 8;
  float* fw    = (float*)(w2l + (size_t)NREC_W2 * 8);
  float* wff1T = fw;              // 700 floats
  float* wembT = fw + NF1T;       // 588 floats
  float* wdyT  = fw + NF1T + NEMT; // 900 floats

  const int prep_tot = NPREP_W + NF1T + NEMT + NDYT;
  prep_kernel<<<(prep_tot + 255) / 256, 256, 0, stream>>>(
      W1, Wres, W2, W_ff1, W_emb, W_dy,
      w1s, wrh, wrl, w2h, w2l, wff1T, wembT, wdyT);

  const int nb_fe = (B + 1) / 2;
  fe_kernel<<<nb_fe, 64, 0, stream>>>(x, b_emb, Wq, bq, Wk, bk, Wv, bv, Wo, bo,
                                      W_ff2, g_norm, b_norm, b_dy, channels,
                                      wff1T, wembT, wdyT, fbuf, B);

  const int nb_h = (B + 63) / 64;
  head_mfma<<<nb_h, 256, 0, stream>>>(fbuf, w1s, wrh, wrl, w2h, w2l,
                                      b1, b2, bres, g_ln, b_ln, W3, b3,
                                      (float*)d_out, B);
}